// Round 7
// baseline (1603.242 us; speedup 1.0000x reference)
//
#include <hip/hip_runtime.h>

#define NXY 160
#define NT 12
#define SP 25600
#define SLAB_U16 3276800ull          // one hi or lo slab: 8*SP*16 u16
#define SLOT_U16 6553600ull          // hi+lo pair
#define SLAB_U4  409600              // SLAB_U16/8

typedef unsigned short u16;
typedef unsigned int u32;
typedef float f32x16 __attribute__((ext_vector_type(16)));
typedef __bf16 bf16x8 __attribute__((ext_vector_type(8)));

__device__ __forceinline__ int refl(int p){ return p<0 ? -p : (p>=NXY ? 2*(NXY-1)-p : p); }
__device__ __forceinline__ u16 bf16_rn(float x){
    u32 u = __float_as_uint(x);
    return (u16)((u + 0x7fffu + ((u>>16)&1u)) >> 16);
}
__device__ __forceinline__ float bf16_f(u16 h){ return __uint_as_float(((u32)h)<<16); }
__device__ __forceinline__ bf16x8 as_bf(uint4 v){ return __builtin_bit_cast(bf16x8, v); }
__device__ __forceinline__ void glds16(const void* g, void* l){
    __builtin_amdgcn_global_load_lds(
        (const __attribute__((address_space(1))) u32*)g,
        (__attribute__((address_space(3))) u32*)l, 16, 0, 0);
}

// ---- pack weights: chunk c = icb*9+tap (8192 B): [hl 2][MT 4][lane 64][8 u16] -------------------
__global__ void pack_w_kernel(const float* __restrict__ wr, const float* __restrict__ wi,
                              u16* __restrict__ Ap)
{
    const int c = blockIdx.x;                 // 0..71
    const int icb = c/9, tap = c - icb*9;
    const int t = threadIdx.x;
    const int lane = t & 63, MT = t >> 6;
    const int row = lane & 31;
    const int oc = MT*16 + (row & 15);
    const int ri_out = row >> 4;
    const int kh = lane >> 5;
    #pragma unroll
    for (int j = 0; j < 8; ++j){
        int ic = icb*8 + kh*4 + (j>>1);
        int ri = j & 1;
        float wrv = wr[(oc*64+ic)*9 + tap];
        float wiv = wi[(oc*64+ic)*9 + tap];
        float val = (ri_out==0) ? (ri ? -wiv : wrv) : (ri ? wrv : wiv);
        u16 h = bf16_rn(val);
        Ap[(size_t)c*4096 + ((0*4 + MT)*64 + lane)*8 + j] = h;
        Ap[(size_t)c*4096 + ((1*4 + MT)*64 + lane)*8 + j] = bf16_rn(val - bf16_f(h));
    }
}

// ---- pack iter into B-slab layout: [icb 8][px][2 uint4] hi-slab + lo-slab, 2 t per launch -------
__global__ __launch_bounds__(256) void pack_iter_kernel(const float* __restrict__ it_r,
        const float* __restrict__ it_i, u16* __restrict__ H, int t0)
{
    __shared__ u32 smh[8192], sml[8192];
    const int t = t0 + blockIdx.y;
    const int tid = threadIdx.x;
    const int pxl = tid & 127, half = tid >> 7;
    const int px0 = blockIdx.x * 128;
    const int px = px0 + pxl;
    #pragma unroll 4
    for (int i = 0; i < 32; ++i){
        int ic = half*32 + i;
        float r  = it_r[((size_t)ic*NT + t)*SP + px];
        float im = it_i[((size_t)ic*NT + t)*SP + px];
        u16 rh = bf16_rn(r),  ih = bf16_rn(im);
        u16 rl = bf16_rn(r - bf16_f(rh)), il = bf16_rn(im - bf16_f(ih));
        int wofs = pxl*64 + (ic ^ (pxl & 31));
        smh[wofs] = (u32)rh | ((u32)ih << 16);
        sml[wofs] = (u32)rl | ((u32)il << 16);
    }
    __syncthreads();
    u16* slab = H + (size_t)blockIdx.y * SLOT_U16;
    uint4* gdst = half ? ((uint4*)slab + SLAB_U4) : (uint4*)slab;
    const u32* sm = half ? sml : smh;
    #pragma unroll
    for (int icb = 0; icb < 8; ++icb)
        #pragma unroll
        for (int q = 0; q < 2; ++q){
            uint4 v;
            #pragma unroll
            for (int d = 0; d < 4; ++d)
                ((u32*)&v)[d] = sm[pxl*64 + ((icb*8 + q*4 + d) ^ (pxl & 31))];
            gdst[((size_t)icb*SP + px)*2 + q] = v;
        }
}

// ---- i2h: 2-channel input conv + ALL biases -> pre (float2 [t][64][SP]) -------------------------
__global__ __launch_bounds__(256) void i2h_kernel(
    const float* __restrict__ in_r, const float* __restrict__ in_i,
    const float* __restrict__ w2r,  const float* __restrict__ w2i,
    const float* __restrict__ b2r,  const float* __restrict__ b2i,
    const float* __restrict__ bihr, const float* __restrict__ bihi,
    const float* __restrict__ bhhr, const float* __restrict__ bhhi,
    float2* __restrict__ pre)
{
    const int t = blockIdx.z, oc0 = blockIdx.y*8;
    const int px = blockIdx.x*256 + threadIdx.x;
    const int x = px/NXY, y = px - x*NXY;
    int offs[9];
    #pragma unroll
    for (int dx=-1; dx<=1; ++dx)
        #pragma unroll
        for (int dy=-1; dy<=1; ++dy)
            offs[(dx+1)*3+(dy+1)] = refl(x+dx)*NXY + refl(y+dy);
    float xr[2][9], xi[2][9];
    #pragma unroll
    for (int ic=0; ic<2; ++ic)
        #pragma unroll
        for (int k=0; k<9; ++k){
            xr[ic][k] = in_r[((size_t)ic*NT+t)*SP + offs[k]];
            xi[ic][k] = in_i[((size_t)ic*NT+t)*SP + offs[k]];
        }
    #pragma unroll
    for (int o=0; o<8; ++o){
        int oc = oc0+o;
        float ar = b2r[oc]+bihr[oc]+bhhr[oc];
        float ai = b2i[oc]+bihi[oc]+bhhi[oc];
        #pragma unroll
        for (int ic=0; ic<2; ++ic)
            #pragma unroll
            for (int k=0; k<9; ++k){
                float wr = w2r[(oc*2+ic)*9+k], wi = w2i[(oc*2+ic)*9+k];
                ar = fmaf(xr[ic][k], wr, ar); ar = fmaf(-xi[ic][k], wi, ar);
                ai = fmaf(xr[ic][k], wi, ai); ai = fmaf( xi[ic][k], wr, ai);
            }
        pre[((size_t)t*64+oc)*SP + px] = make_float2(ar, ai);
    }
}

// ---- GEMM: 32x32x16, 4 waves (2M x 2N), 8x16-px tile, A L2->reg, B halo LDS, 1 barrier/icb -----
#define MF(a,b,c) __builtin_amdgcn_mfma_f32_32x32x16_bf16(a,b,c,0,0,0)
// B LDS phys layout (uint4 idx): (hl*2 + (q ^ (hx&1)))*180 + hx*18 + hy ; buf stride 768
#define B_OFF(nt, DX, DY) ( ((DX)==0 ? bE[nt] : (bO[nt] + ((DX)==1 ? 576 : 0))) \
                            + ((DY)+1)*16 + bufoff )

#define TAPBODY(DX, DY, CUR, NXT, DONEXT, NEXTC)                                \
{                                                                               \
    uint4 rbh0 = *(const uint4*)((const char*)ldsB + B_OFF(0,DX,DY));           \
    uint4 rbl0 = *(const uint4*)((const char*)ldsB + B_OFF(0,DX,DY) + 5760);    \
    uint4 rbh1 = *(const uint4*)((const char*)ldsB + B_OFF(1,DX,DY));           \
    uint4 rbl1 = *(const uint4*)((const char*)ldsB + B_OFF(1,DX,DY) + 5760);    \
    if (DONEXT){                                                                \
        NXT[0][0] = Ag[(size_t)(NEXTC)*512 + (0*4 + mgrp*2+0)*64 + lane];       \
        NXT[0][1] = Ag[(size_t)(NEXTC)*512 + (1*4 + mgrp*2+0)*64 + lane];       \
        NXT[1][0] = Ag[(size_t)(NEXTC)*512 + (0*4 + mgrp*2+1)*64 + lane];       \
        NXT[1][1] = Ag[(size_t)(NEXTC)*512 + (1*4 + mgrp*2+1)*64 + lane];       \
    }                                                                           \
    bf16x8 bh0=as_bf(rbh0), bl0=as_bf(rbl0), bh1=as_bf(rbh1), bl1=as_bf(rbl1);  \
    bf16x8 a0h=as_bf(CUR[0][0]), a0l=as_bf(CUR[0][1]);                          \
    bf16x8 a1h=as_bf(CUR[1][0]), a1l=as_bf(CUR[1][1]);                          \
    acc[0][0]=MF(a0h,bh0,acc[0][0]); acc[0][1]=MF(a0h,bh1,acc[0][1]);           \
    acc[1][0]=MF(a1h,bh0,acc[1][0]); acc[1][1]=MF(a1h,bh1,acc[1][1]);           \
    acc[0][0]=MF(a0h,bl0,acc[0][0]); acc[0][1]=MF(a0h,bl1,acc[0][1]);           \
    acc[1][0]=MF(a1h,bl0,acc[1][0]); acc[1][1]=MF(a1h,bl1,acc[1][1]);           \
    acc[0][0]=MF(a0l,bh0,acc[0][0]); acc[0][1]=MF(a0l,bh1,acc[0][1]);           \
    acc[1][0]=MF(a1l,bh0,acc[1][0]); acc[1][1]=MF(a1l,bh1,acc[1][1]);           \
}

template<int MODE>
__global__ __launch_bounds__(256, 2) void gemm_kernel(
    const uint4* __restrict__ A4,      // [72 chunks][hl][4 MT][64 lane] uint4
    const u16* __restrict__ Hbase,
    float2* __restrict__ pre_b,
    float2* __restrict__ out,
    const float* __restrict__ modb,
    u16* __restrict__ Hw,
    int s)
{
    __shared__ uint4 ldsB[1536];       // 2 buf x 768 (720 used + pad)
    const int tid = threadIdx.x;
    const int lane = tid & 63, w = tid >> 6;
    const int mgrp = w >> 1, ngrp = w & 1;
    const int l31 = lane & 31, kh = lane >> 5;
    const int c15 = l31 & 15, rb = l31 >> 4;
    const int T = blockIdx.x;
    const int x0 = (T/10)*8, y0 = (T - (T/10)*10)*16;

    const uint4* Bh4; float2* pre_t;
    int dir = 0, t = 0;
    if constexpr (MODE==0){
        Bh4 = (const uint4*)(Hbase + (size_t)blockIdx.y * SLOT_U16);
        pre_t = pre_b + (size_t)blockIdx.y * 64 * SP;
    } else {
        dir = blockIdx.y;
        int rp = (s+1) & 1;
        Bh4 = (const uint4*)(Hbase + (size_t)(dir*2+rp) * SLOT_U16);
        t = dir ? (NT-1-s) : s;
        pre_t = pre_b + (size_t)t * 64 * SP;
    }

    f32x16 acc[2][2];
    #pragma unroll
    for (int mt=0; mt<2; ++mt)
        #pragma unroll
        for (int nt=0; nt<2; ++nt) acc[mt][nt] = (f32x16)0.f;

    const bool hasK = (MODE==0) || (s > 0);
    if (hasK){
        const uint4* Ag = A4;

        auto stageB = [&](int icb, int buf){
            #pragma unroll
            for (int i=0;i<3;++i){
                int e = i*256 + tid;               // 0..767 (dest; >=720 lands in pad)
                int es = e >= 720 ? e-720 : e;     // source entry
                int hlq = es/180, hp = es - hlq*180;
                int hl = hlq>>1, qd = hlq&1;
                int hx = hp/18, hy = hp - hx*18;
                int qs = qd ^ (hx&1);
                int gx = refl(x0-1+hx), gy = refl(y0-1+hy);
                glds16(Bh4 + (size_t)hl*SLAB_U4 + ((size_t)icb*SP + gx*NXY+gy)*2 + qs,
                       (char*)ldsB + buf*12288 + e*16);
            }
        };

        // B read bases (byte offsets into ldsB), per nt and dx-parity class
        int bO[2], bE[2];
        #pragma unroll
        for (int nt=0; nt<2; ++nt){
            int r = ngrp*4 + nt*2 + rb;
            int hxO = r;         // dx=-1 basis (hx = r+1+dx)
            int hxE = r + 1;     // dx=0
            bO[nt] = (((kh ^ (hxO&1))*180) + hxO*18 + c15) * 16;
            bE[nt] = (((kh ^ (hxE&1))*180) + hxE*18 + c15) * 16;
        }

        uint4 aA[2][2], aB[2][2];
        stageB(0, 0);
        aA[0][0] = Ag[(0*4 + mgrp*2+0)*64 + lane];
        aA[0][1] = Ag[(1*4 + mgrp*2+0)*64 + lane];
        aA[1][0] = Ag[(0*4 + mgrp*2+1)*64 + lane];
        aA[1][1] = Ag[(1*4 + mgrp*2+1)*64 + lane];
        __syncthreads();

        for (int icb = 0; icb < 8; ++icb){
            const int bufoff = (icb&1)*12288;
            const int cb = icb*9;
            const bool more = (icb < 7);
            if (more) stageB(icb+1, (icb&1)^1);
            TAPBODY(-1,-1, aA, aB, true, cb+1)
            TAPBODY(-1, 0, aB, aA, true, cb+2)
            TAPBODY(-1, 1, aA, aB, true, cb+3)
            TAPBODY( 0,-1, aB, aA, true, cb+4)
            TAPBODY( 0, 0, aA, aB, true, cb+5)
            TAPBODY( 0, 1, aB, aA, true, cb+6)
            TAPBODY( 1,-1, aA, aB, true, cb+7)
            TAPBODY( 1, 0, aB, aA, true, cb+8)
            TAPBODY( 1, 1, aA, aB, more, cb+9)
            if (more){
                aA[0][0]=aB[0][0]; aA[0][1]=aB[0][1];
                aA[1][0]=aB[1][0]; aA[1][1]=aB[1][1];
            }
            __syncthreads();
        }
    }

    if constexpr (MODE==0){
        #pragma unroll
        for (int mt=0; mt<2; ++mt){
            const int MT = mgrp*2 + mt;
            #pragma unroll
            for (int nt=0; nt<2; ++nt){
                const int row = ngrp*4 + nt*2 + rb;
                const int px = (x0+row)*NXY + y0 + c15;
                #pragma unroll
                for (int g=0; g<2; ++g)
                    #pragma unroll
                    for (int d=0; d<4; ++d){
                        int oc = MT*16 + kh*4 + d + 8*g;
                        float2 p = pre_t[(size_t)oc*SP + px];
                        p.x += acc[mt][nt][g*4+d];
                        p.y += acc[mt][nt][g*4+d+8];
                        pre_t[(size_t)oc*SP + px] = p;
                    }
            }
        }
    } else {
        u16* Chw = Hw + (size_t)(dir*2 + (s&1)) * SLOT_U16;
        uint4* Ch4w = (uint4*)Chw;
        uint4* Cl4w = Ch4w + SLAB_U4;
        const bool first = (s <= 5);
        #pragma unroll
        for (int mt=0; mt<2; ++mt){
            const int MT = mgrp*2 + mt;
            #pragma unroll
            for (int nt=0; nt<2; ++nt){
                const int row = ngrp*4 + nt*2 + rb;
                const int px = (x0+row)*NXY + y0 + c15;
                #pragma unroll
                for (int g=0; g<2; ++g){
                    uint4 hv, lv;
                    #pragma unroll
                    for (int d=0; d<4; ++d){
                        int oc = MT*16 + kh*4 + d + 8*g;
                        float2 p = pre_t[(size_t)oc*SP + px];
                        float zr = p.x + acc[mt][nt][g*4+d];
                        float zi = p.y + acc[mt][nt][g*4+d+8];
                        float mag = sqrtf(zr*zr + zi*zi);
                        float sc = fmaxf(mag + modb[oc], 0.f) / (mag + 1e-8f);
                        float hr = sc*zr, hm = sc*zi;
                        size_t oidx = ((size_t)oc*NT + t)*SP + px;
                        if (first) out[oidx] = make_float2(hr, hm);
                        else { float2 o2 = out[oidx]; out[oidx] = make_float2(o2.x+hr, o2.y+hm); }
                        u16 rh = bf16_rn(hr), ih = bf16_rn(hm);
                        u16 rl = bf16_rn(hr - bf16_f(rh)), il = bf16_rn(hm - bf16_f(ih));
                        ((u32*)&hv)[d] = (u32)rh | ((u32)ih<<16);
                        ((u32*)&lv)[d] = (u32)rl | ((u32)il<<16);
                    }
                    int icbh = MT*2 + g;
                    size_t q = ((size_t)icbh*SP + px)*2 + kh;
                    Ch4w[q] = hv; Cl4w[q] = lv;
                }
            }
        }
    }
}

extern "C" void kernel_launch(void* const* d_in, const int* in_sizes, int n_in,
                              void* d_out, int out_size, void* d_ws, size_t ws_size,
                              hipStream_t stream)
{
    const float* in_r  = (const float*)d_in[0];
    const float* in_i  = (const float*)d_in[1];
    const float* it_r  = (const float*)d_in[2];
    const float* it_i  = (const float*)d_in[3];
    const float* w2_r  = (const float*)d_in[4];
    const float* w2_i  = (const float*)d_in[5];
    const float* b2_r  = (const float*)d_in[6];
    const float* b2_i  = (const float*)d_in[7];
    const float* whh_r = (const float*)d_in[8];
    const float* whh_i = (const float*)d_in[9];
    const float* bhh_r = (const float*)d_in[10];
    const float* bhh_i = (const float*)d_in[11];
    const float* wih_r = (const float*)d_in[12];
    const float* wih_i = (const float*)d_in[13];
    const float* bih_r = (const float*)d_in[14];
    const float* bih_i = (const float*)d_in[15];
    const float* mod_b = (const float*)d_in[16];

    char* ws = (char*)d_ws;
    float2* pre = (float2*)ws;                             // 157,286,400 B
    u16*    H   = (u16*)(ws + 157286400);                  //  52,428,800 B (4 slots)
    u16*    Ahh = (u16*)(ws + 157286400 + 52428800);       //     589,824 B
    u16*    Aih = H + 2*SLOT_U16;                          // overlaps slots 2,3 (dead in MODE0 phase)
    float2* out = (float2*)d_out;

    pack_w_kernel<<<72, 256, 0, stream>>>(whh_r, whh_i, Ahh);
    pack_w_kernel<<<72, 256, 0, stream>>>(wih_r, wih_i, Aih);
    i2h_kernel<<<dim3(100,8,12), 256, 0, stream>>>(in_r, in_i, w2_r, w2_i,
        b2_r, b2_i, bih_r, bih_i, bhh_r, bhh_i, pre);
    for (int t0 = 0; t0 < NT; t0 += 2){
        pack_iter_kernel<<<dim3(200,2), 256, 0, stream>>>(it_r, it_i, H, t0);
        gemm_kernel<0><<<dim3(200,2), 256, 0, stream>>>((const uint4*)Aih, H,
            pre + (size_t)t0*64*SP, nullptr, nullptr, nullptr, 0);
    }
    for (int s = 0; s < NT; ++s)
        gemm_kernel<1><<<dim3(200,2), 256, 0, stream>>>((const uint4*)Ahh, H,
            pre, out, mod_b, H, s);
}

// Round 8
// 1411.027 us; speedup vs baseline: 1.1362x; 1.1362x over previous
//
#include <hip/hip_runtime.h>

#define NXY 160
#define NT 12
#define SP 25600
#define SLAB_U16 3276800ull          // one hi or lo slab: 8*SP*16 u16
#define SLOT_U16 6553600ull          // hi+lo pair
#define SLAB_U4  409600              // SLAB_U16/8

typedef unsigned short u16;
typedef unsigned int u32;
typedef float f32x16 __attribute__((ext_vector_type(16)));
typedef __bf16 bf16x8 __attribute__((ext_vector_type(8)));

__device__ __forceinline__ int refl(int p){ return p<0 ? -p : (p>=NXY ? 2*(NXY-1)-p : p); }
__device__ __forceinline__ u16 bf16_rn(float x){
    u32 u = __float_as_uint(x);
    return (u16)((u + 0x7fffu + ((u>>16)&1u)) >> 16);
}
__device__ __forceinline__ float bf16_f(u16 h){ return __uint_as_float(((u32)h)<<16); }
__device__ __forceinline__ bf16x8 as_bf(uint4 v){ return __builtin_bit_cast(bf16x8, v); }
__device__ __forceinline__ void glds16(const uint4* g, uint4* l){
    __builtin_amdgcn_global_load_lds(
        (const __attribute__((address_space(1))) u32*)g,
        (__attribute__((address_space(3))) u32*)l, 16, 0, 0);
}

// ---- pack weights: chunk c = icb*9+tap (8192 B): [hl 2][MT 4][lane 64][8 u16] -------------------
__global__ void pack_w_kernel(const float* __restrict__ wr, const float* __restrict__ wi,
                              u16* __restrict__ Ap)
{
    const int c = blockIdx.x;                 // 0..71
    const int icb = c/9, tap = c - icb*9;
    const int t = threadIdx.x;
    const int lane = t & 63, MT = t >> 6;
    const int row = lane & 31;
    const int oc = MT*16 + (row & 15);
    const int ri_out = row >> 4;
    const int kh = lane >> 5;
    #pragma unroll
    for (int j = 0; j < 8; ++j){
        int ic = icb*8 + kh*4 + (j>>1);
        int ri = j & 1;
        float wrv = wr[(oc*64+ic)*9 + tap];
        float wiv = wi[(oc*64+ic)*9 + tap];
        float val = (ri_out==0) ? (ri ? -wiv : wrv) : (ri ? wrv : wiv);
        u16 h = bf16_rn(val);
        Ap[(size_t)c*4096 + ((0*4 + MT)*64 + lane)*8 + j] = h;
        Ap[(size_t)c*4096 + ((1*4 + MT)*64 + lane)*8 + j] = bf16_rn(val - bf16_f(h));
    }
}

// ---- pack iter ALL t into B-slab layout: [icb 8][px][2 uint4] hi + lo slab ----------------------
__global__ __launch_bounds__(256) void pack_iter_kernel(const float* __restrict__ it_r,
        const float* __restrict__ it_i, u16* __restrict__ Pit)
{
    __shared__ u32 smh[8192], sml[8192];
    const int t = blockIdx.y;
    const int tid = threadIdx.x;
    const int pxl = tid & 127, half = tid >> 7;
    const int px0 = blockIdx.x * 128;
    const int px = px0 + pxl;
    #pragma unroll 4
    for (int i = 0; i < 32; ++i){
        int ic = half*32 + i;
        float r  = it_r[((size_t)ic*NT + t)*SP + px];
        float im = it_i[((size_t)ic*NT + t)*SP + px];
        u16 rh = bf16_rn(r),  ih = bf16_rn(im);
        u16 rl = bf16_rn(r - bf16_f(rh)), il = bf16_rn(im - bf16_f(ih));
        int wofs = pxl*64 + (ic ^ (pxl & 31));
        smh[wofs] = (u32)rh | ((u32)ih << 16);
        sml[wofs] = (u32)rl | ((u32)il << 16);
    }
    __syncthreads();
    u16* slab = Pit + (size_t)t * SLOT_U16;
    uint4* gdst = half ? ((uint4*)slab + SLAB_U4) : (uint4*)slab;
    const u32* sm = half ? sml : smh;
    #pragma unroll
    for (int icb = 0; icb < 8; ++icb)
        #pragma unroll
        for (int q = 0; q < 2; ++q){
            uint4 v;
            #pragma unroll
            for (int d = 0; d < 4; ++d)
                ((u32*)&v)[d] = sm[pxl*64 + ((icb*8 + q*4 + d) ^ (pxl & 31))];
            gdst[((size_t)icb*SP + px)*2 + q] = v;
        }
}

// ---- i2h: 2-channel input conv + ALL biases -> pre (float2 [t][64][SP]) -------------------------
__global__ __launch_bounds__(256) void i2h_kernel(
    const float* __restrict__ in_r, const float* __restrict__ in_i,
    const float* __restrict__ w2r,  const float* __restrict__ w2i,
    const float* __restrict__ b2r,  const float* __restrict__ b2i,
    const float* __restrict__ bihr, const float* __restrict__ bihi,
    const float* __restrict__ bhhr, const float* __restrict__ bhhi,
    float2* __restrict__ pre)
{
    const int t = blockIdx.z, oc0 = blockIdx.y*8;
    const int px = blockIdx.x*256 + threadIdx.x;
    const int x = px/NXY, y = px - x*NXY;
    int offs[9];
    #pragma unroll
    for (int dx=-1; dx<=1; ++dx)
        #pragma unroll
        for (int dy=-1; dy<=1; ++dy)
            offs[(dx+1)*3+(dy+1)] = refl(x+dx)*NXY + refl(y+dy);
    float xr[2][9], xi[2][9];
    #pragma unroll
    for (int ic=0; ic<2; ++ic)
        #pragma unroll
        for (int k=0; k<9; ++k){
            xr[ic][k] = in_r[((size_t)ic*NT+t)*SP + offs[k]];
            xi[ic][k] = in_i[((size_t)ic*NT+t)*SP + offs[k]];
        }
    #pragma unroll
    for (int o=0; o<8; ++o){
        int oc = oc0+o;
        float ar = b2r[oc]+bihr[oc]+bhhr[oc];
        float ai = b2i[oc]+bihi[oc]+bhhi[oc];
        #pragma unroll
        for (int ic=0; ic<2; ++ic)
            #pragma unroll
            for (int k=0; k<9; ++k){
                float wr = w2r[(oc*2+ic)*9+k], wi = w2i[(oc*2+ic)*9+k];
                ar = fmaf(xr[ic][k], wr, ar); ar = fmaf(-xi[ic][k], wi, ar);
                ai = fmaf(xr[ic][k], wi, ai); ai = fmaf( xi[ic][k], wr, ai);
            }
        pre[((size_t)t*64+oc)*SP + px] = make_float2(ar, ai);
    }
}

// ---- GEMM: 32x32x16, 4 waves (2M x 2N), tile 8x x 16y, counted-vmcnt pipeline -------------------
#define MF(a,b,c) __builtin_amdgcn_mfma_f32_32x32x16_bf16(a,b,c,0,0,0)

#define TAP(T_, AB, SB, BX0, BX1, DY, STA, STB, VM)                            \
{                                                                              \
    if (STA) stageA(gbase + (T_) + 2, SB);                                     \
    if (STB) stageB(icbn, bbn);                                                \
    uint4 a0h = As[(AB)*512 + (0*4+MT0)*64 + lane];                            \
    uint4 a1h = As[(AB)*512 + (0*4+MT1)*64 + lane];                            \
    uint4 a0l = As[(AB)*512 + (1*4+MT0)*64 + lane];                            \
    uint4 a1l = As[(AB)*512 + (1*4+MT1)*64 + lane];                            \
    int bi0 = bbOff + (BX0) + (DY);                                            \
    int bi1 = bbOff + (BX1) + (DY);                                            \
    uint4 b0h = Bs[bi0];       uint4 b1h = Bs[bi1];                            \
    uint4 b0l = Bs[bi0 + 360]; uint4 b1l = Bs[bi1 + 360];                      \
    bf16x8 A0H=as_bf(a0h), A1H=as_bf(a1h), A0L=as_bf(a0l), A1L=as_bf(a1l);     \
    bf16x8 B0H=as_bf(b0h), B1H=as_bf(b1h), B0L=as_bf(b0l), B1L=as_bf(b1l);     \
    __builtin_amdgcn_s_setprio(1);                                             \
    acc00 = MF(A0H,B0H,acc00); acc01 = MF(A0H,B1H,acc01);                      \
    acc10 = MF(A1H,B0H,acc10); acc11 = MF(A1H,B1H,acc11);                      \
    acc00 = MF(A0H,B0L,acc00); acc01 = MF(A0H,B1L,acc01);                      \
    acc10 = MF(A1H,B0L,acc10); acc11 = MF(A1H,B1L,acc11);                      \
    acc00 = MF(A0L,B0H,acc00); acc01 = MF(A0L,B1H,acc01);                      \
    acc10 = MF(A1L,B0H,acc10); acc11 = MF(A1L,B1H,acc11);                      \
    __builtin_amdgcn_s_setprio(0);                                             \
    asm volatile("s_waitcnt vmcnt(" VM ")" ::: "memory");                      \
    __builtin_amdgcn_s_barrier();                                              \
    __builtin_amdgcn_sched_barrier(0);                                         \
}

#define EPI0(ACC, MT_, PX_)                                                    \
        _Pragma("unroll")                                                      \
        for (int g=0; g<2; ++g)                                                \
            _Pragma("unroll")                                                  \
            for (int d=0; d<4; ++d){                                           \
                int oc = (MT_)*16 + kh*4 + d + 8*g;                            \
                float2 p = pre_t[(size_t)oc*SP + (PX_)];                       \
                p.x += ACC[g*4+d];                                             \
                p.y += ACC[g*4+d+8];                                           \
                pre_t[(size_t)oc*SP + (PX_)] = p;                              \
            }

#define EPI1(ACC, MT_, PX_)                                                    \
        _Pragma("unroll")                                                      \
        for (int g=0; g<2; ++g){                                               \
            uint4 hv, lv;                                                      \
            _Pragma("unroll")                                                  \
            for (int d=0; d<4; ++d){                                           \
                int oc = (MT_)*16 + kh*4 + d + 8*g;                            \
                float2 p = pre_t[(size_t)oc*SP + (PX_)];                       \
                float zr = p.x + ACC[g*4+d];                                   \
                float zi = p.y + ACC[g*4+d+8];                                 \
                float mag = sqrtf(zr*zr + zi*zi);                              \
                float sc = fmaxf(mag + modb[oc], 0.f) / (mag + 1e-8f);         \
                float hr = sc*zr, hm = sc*zi;                                  \
                size_t oidx = ((size_t)oc*NT + t)*SP + (PX_);                  \
                if (first) out[oidx] = make_float2(hr, hm);                    \
                else { float2 o2 = out[oidx]; out[oidx] = make_float2(o2.x+hr, o2.y+hm); } \
                u16 rh = bf16_rn(hr), ih = bf16_rn(hm);                        \
                u16 rl = bf16_rn(hr - bf16_f(rh)), il = bf16_rn(hm - bf16_f(ih)); \
                ((u32*)&hv)[d] = (u32)rh | ((u32)ih<<16);                      \
                ((u32*)&lv)[d] = (u32)rl | ((u32)il<<16);                      \
            }                                                                  \
            size_t q = ((size_t)((MT_)*2+g)*SP + (PX_))*2 + kh;                \
            Ch4w[q] = hv; Cl4w[q] = lv;                                        \
        }

template<int MODE>
__global__ __launch_bounds__(256, 3) void gemm_kernel(
    const uint4* __restrict__ A4,      // [72 chunks][hl 2][MT 4][lane 64] uint4
    const u16* __restrict__ Bsrc,      // MODE0: pit (12 slots); MODE1: H (4 slots)
    float2* __restrict__ pre_b,
    float2* __restrict__ out,
    const float* __restrict__ modb,
    u16* __restrict__ Hw,
    int s)
{
    __shared__ uint4 As[1536];         // 3 x 8KB A chunk buffers
    __shared__ uint4 Bs[1536];         // 2 x 12KB B halo buffers (720 used + pad)
    const int tid = threadIdx.x;
    const int lane = tid & 63, w = tid >> 6;
    const int mgrp = w >> 1, ngrp = w & 1;
    const int l31 = lane & 31, kh = lane >> 5;
    const int c15 = l31 & 15, rb = l31 >> 4;
    const int T = blockIdx.x;
    const int x0 = (T/10)*8, y0 = (T - (T/10)*10)*16;
    const int MT0 = mgrp*2, MT1 = mgrp*2 + 1;

    const uint4* Bh4; float2* pre_t;
    int dir = 0, t = 0;
    if constexpr (MODE==0){
        t = blockIdx.y;
        Bh4 = (const uint4*)(Bsrc + (size_t)t * SLOT_U16);
        pre_t = pre_b + (size_t)t * 64 * SP;
    } else {
        dir = blockIdx.y;
        int rp = (s+1) & 1;
        Bh4 = (const uint4*)(Bsrc + (size_t)(dir*2+rp) * SLOT_U16);
        t = dir ? (NT-1-s) : s;
        pre_t = pre_b + (size_t)t * 64 * SP;
    }

    f32x16 acc00 = (f32x16)0.f, acc01 = (f32x16)0.f;
    f32x16 acc10 = (f32x16)0.f, acc11 = (f32x16)0.f;

    const bool hasK = (MODE==0) || (s > 0);
    if (hasK){
        // B-stage source offsets (per thread, 3 entries), excluding icb term
        int sB0, sB1, sB2;
        {
            #pragma unroll
            for (int i=0;i<3;++i){
                int e = i*256 + tid;
                int es = e >= 720 ? e - 720 : e;
                int hlq = es/180, hp = es - hlq*180;
                int hl = hlq>>1, qd = hlq&1;
                int hx = hp/18, hy = hp - hx*18;
                int qs = qd ^ (hx&1);
                int gx = refl(x0-1+hx), gy = refl(y0-1+hy);
                int v = hl*SLAB_U4 + (gx*NXY+gy)*2 + qs;
                if (i==0) sB0 = v; else if (i==1) sB1 = v; else sB2 = v;
            }
        }
        auto stageA = [&](int c, int buf){
            glds16(A4 + (size_t)c*512 + tid,       As + buf*512 + tid);
            glds16(A4 + (size_t)c*512 + 256 + tid, As + buf*512 + 256 + tid);
        };
        auto stageB = [&](int icb, int buf){
            const uint4* base = Bh4 + (size_t)icb*51200;
            glds16(base + sB0, Bs + buf*768 + tid);
            glds16(base + sB1, Bs + buf*768 + 256 + tid);
            glds16(base + sB2, Bs + buf*768 + 512 + tid);
        };

        // B read bases (uint4 idx, hl=0): E = dx=0, O = dx=-1 (dx=+1 -> O+36)
        int bE0, bE1, bO0, bO1;
        {
            int hxb0 = ngrp*4 + 0 + rb + 1;
            int hxb1 = ngrp*4 + 2 + rb + 1;
            bE0 = (kh ^ (hxb0&1))*180 + hxb0*18 + c15 + 1;
            bO0 = (kh ^ 1 ^ (hxb0&1))*180 + (hxb0-1)*18 + c15 + 1;
            bE1 = (kh ^ (hxb1&1))*180 + hxb1*18 + c15 + 1;
            bO1 = (kh ^ 1 ^ (hxb1&1))*180 + (hxb1-1)*18 + c15 + 1;
        }

        stageA(0, 0); stageA(1, 1); stageB(0, 0);
        asm volatile("s_waitcnt vmcnt(0)" ::: "memory");
        __builtin_amdgcn_s_barrier();
        __builtin_amdgcn_sched_barrier(0);

        for (int icb = 0; icb < 7; ++icb){
            const int gbase = icb*9;
            const int bbOff = (icb&1)*768;
            const int icbn  = icb+1;
            const int bbn   = (icb&1)^1;
            TAP(0, 0, 2, bO0,    bO1,    -1, 1, 0, "2")
            TAP(1, 1, 0, bO0,    bO1,     0, 1, 0, "2")
            TAP(2, 2, 1, bO0,    bO1,     1, 1, 0, "2")
            TAP(3, 0, 2, bE0,    bE1,    -1, 1, 0, "2")
            TAP(4, 1, 0, bE0,    bE1,     0, 1, 0, "2")
            TAP(5, 2, 1, bE0,    bE1,     1, 1, 0, "2")
            TAP(6, 0, 2, bO0+36, bO1+36, -1, 1, 0, "2")
            TAP(7, 1, 0, bO0+36, bO1+36,  0, 1, 1, "5")
            TAP(8, 2, 1, bO0+36, bO1+36,  1, 1, 0, "2")
        }
        {   // peeled icb = 7
            const int gbase = 63;
            const int bbOff = 768;
            const int icbn  = 0;
            const int bbn   = 0;
            TAP(0, 0, 2, bO0,    bO1,    -1, 1, 0, "2")
            TAP(1, 1, 0, bO0,    bO1,     0, 1, 0, "2")
            TAP(2, 2, 1, bO0,    bO1,     1, 1, 0, "2")
            TAP(3, 0, 2, bE0,    bE1,    -1, 1, 0, "2")
            TAP(4, 1, 0, bE0,    bE1,     0, 1, 0, "2")
            TAP(5, 2, 1, bE0,    bE1,     1, 1, 0, "2")
            TAP(6, 0, 2, bO0+36, bO1+36, -1, 1, 0, "2")
            TAP(7, 1, 0, bO0+36, bO1+36,  0, 0, 0, "0")
            TAP(8, 2, 1, bO0+36, bO1+36,  1, 0, 0, "0")
        }
    }

    const int pxA = (x0 + ngrp*4 + 0 + rb)*NXY + y0 + c15;   // nt0
    const int pxB = (x0 + ngrp*4 + 2 + rb)*NXY + y0 + c15;   // nt1

    if constexpr (MODE==0){
        EPI0(acc00, MT0, pxA)
        EPI0(acc01, MT0, pxB)
        EPI0(acc10, MT1, pxA)
        EPI0(acc11, MT1, pxB)
    } else {
        u16* Chw = Hw + (size_t)(dir*2 + (s&1)) * SLOT_U16;
        uint4* Ch4w = (uint4*)Chw;
        uint4* Cl4w = Ch4w + SLAB_U4;
        const bool first = (s <= 5);
        EPI1(acc00, MT0, pxA)
        EPI1(acc01, MT0, pxB)
        EPI1(acc10, MT1, pxA)
        EPI1(acc11, MT1, pxB)
    }
}

extern "C" void kernel_launch(void* const* d_in, const int* in_sizes, int n_in,
                              void* d_out, int out_size, void* d_ws, size_t ws_size,
                              hipStream_t stream)
{
    const float* in_r  = (const float*)d_in[0];
    const float* in_i  = (const float*)d_in[1];
    const float* it_r  = (const float*)d_in[2];
    const float* it_i  = (const float*)d_in[3];
    const float* w2_r  = (const float*)d_in[4];
    const float* w2_i  = (const float*)d_in[5];
    const float* b2_r  = (const float*)d_in[6];
    const float* b2_i  = (const float*)d_in[7];
    const float* whh_r = (const float*)d_in[8];
    const float* whh_i = (const float*)d_in[9];
    const float* bhh_r = (const float*)d_in[10];
    const float* bhh_i = (const float*)d_in[11];
    const float* wih_r = (const float*)d_in[12];
    const float* wih_i = (const float*)d_in[13];
    const float* bih_r = (const float*)d_in[14];
    const float* bih_i = (const float*)d_in[15];
    const float* mod_b = (const float*)d_in[16];

    char* ws = (char*)d_ws;
    float2* pre = (float2*)ws;                             // 157,286,400 B
    u16*    H   = (u16*)(ws + 157286400);                  //  52,428,800 B (4 slots)
    u16*    Ahh = (u16*)(ws + 157286400 + 52428800);       //     589,824 B
    u16*    Aih = H + 2*SLOT_U16;                          // overlaps H slots 2,3 (dead until MODE1 s=0)
    u16*    Pit = (u16*)d_out;                             // 12 slots = 157,286,400 B (dead before out-writes)
    float2* out = (float2*)d_out;

    pack_w_kernel<<<72, 256, 0, stream>>>(whh_r, whh_i, Ahh);
    pack_w_kernel<<<72, 256, 0, stream>>>(wih_r, wih_i, Aih);
    pack_iter_kernel<<<dim3(200,12), 256, 0, stream>>>(it_r, it_i, Pit);
    i2h_kernel<<<dim3(100,8,12), 256, 0, stream>>>(in_r, in_i, w2_r, w2_i,
        b2_r, b2_i, bih_r, bih_i, bhh_r, bhh_i, pre);
    gemm_kernel<0><<<dim3(200,12), 256, 0, stream>>>((const uint4*)Aih, Pit,
        pre, nullptr, nullptr, nullptr, 0);
    for (int s = 0; s < NT; ++s)
        gemm_kernel<1><<<dim3(200,2), 256, 0, stream>>>((const uint4*)Ahh, H,
            pre, out, mod_b, H, s);
}